// Round 1
// baseline (78.252 us; speedup 1.0000x reference)
//
#include <hip/hip_runtime.h>
#include <hip/hip_bf16.h>

#define B_ 128
#define I_ 2048
#define O_ 2048
#define SEG 10
#define BK 32
#define NSTEP (I_ / BK)   // 64
#define LDSROW 40         // bf16 elems per row: 32 + 8 pad -> 80 B stride

typedef __attribute__((ext_vector_type(8))) short bf16x8;
typedef __attribute__((ext_vector_type(4))) float f32x4;

static __device__ __forceinline__ unsigned short f2bf(float f) {
    // round-to-nearest-even fp32 -> bf16 (inputs are finite normals)
    unsigned u = __float_as_uint(f);
    u += 0x7FFFu + ((u >> 16) & 1u);
    return (unsigned short)(u >> 16);
}

__global__ __launch_bounds__(256, 2) void neuro_fused(
    const float* __restrict__ x,      // [B_, I_]
    const float* __restrict__ ctx,    // [O_]
    const float* __restrict__ w,      // [O_, I_]
    const float* __restrict__ bias,   // [O_]
    const float* __restrict__ astro,  // [O_]
    const float* __restrict__ D,      // [O_, I_, SEG]
    float* __restrict__ out)          // [B_, O_]
{
    __shared__ __align__(16) short xs[128 * LDSROW];  // 10240 B, bf16 x-tile

    const int tid  = threadIdx.x;
    const int wave = tid >> 6;
    const int lane = tid & 63;
    const int o    = blockIdx.x * 4 + wave;
    const int col  = lane & 15;   // MFMA n-index / C col
    const int g    = lane >> 4;   // 16-lane group

    // per-lane D/w addressing: cols 0..9 -> dendrite cols, col 10 -> weight row,
    // cols 11..15 -> load weight too (broadcast, harmless) and mask to 0
    const float* dptr;
    int dstride;
    float dmask;
    if (col < 10) {
        dptr = D + (size_t)o * (I_ * SEG) + col;
        dstride = SEG;
        dmask = 1.0f;
    } else {
        dptr = w + (size_t)o * I_;
        dstride = 1;
        dmask = (col == 10) ? 1.0f : 0.0f;
    }

    f32x4 acc[8];
#pragma unroll
    for (int m = 0; m < 8; ++m) acc[m] = (f32x4){0.f, 0.f, 0.f, 0.f};

    // astro gate + bias (uniform per wave; loads are cached)
    float am = astro[o] * ctx[o];
    am = 1.0f / (1.0f + __expf(-am));
    const float bo = bias[o];

    // ---- helpers -------------------------------------------------------
    // x tile t: x[0..127][t*BK .. t*BK+31] fp32, 1024 float4s, 4 per thread
    auto load_x = [&](int t, float4* xr) {
        const float* xp = x + t * BK;
#pragma unroll
        for (int p = 0; p < 4; ++p) {
            int q = tid + 256 * p;
            int row = q >> 3;
            int kq = (q & 7) * 4;
            xr[p] = *reinterpret_cast<const float4*>(xp + (size_t)row * I_ + kq);
        }
    };
    auto store_x = [&](const float4* xr) {
#pragma unroll
        for (int p = 0; p < 4; ++p) {
            int q = tid + 256 * p;
            int row = q >> 3;
            int kq = (q & 7) * 4;
            ushort4 h;
            h.x = f2bf(xr[p].x);
            h.y = f2bf(xr[p].y);
            h.z = f2bf(xr[p].z);
            h.w = f2bf(xr[p].w);
            *reinterpret_cast<ushort4*>(&xs[row * LDSROW + kq]) = h;
        }
    };
    // D fragment for step t: lane needs k = t*BK + 8*g + e, e = 0..7
    auto load_d = [&](int t, float* dr) {
        const int k0 = t * BK + 8 * g;
#pragma unroll
        for (int e = 0; e < 8; ++e)
            dr[e] = dptr[(size_t)(k0 + e) * dstride];
    };
    auto compute = [&](const float* dr) {
        bf16x8 bfrag;
#pragma unroll
        for (int e = 0; e < 8; ++e) bfrag[e] = (short)f2bf(dr[e] * dmask);
#pragma unroll
        for (int m = 0; m < 8; ++m) {
            int row = m * 16 + col;  // A row = lane&15
            bf16x8 afrag = *reinterpret_cast<const bf16x8*>(&xs[row * LDSROW + 8 * g]);
            acc[m] = __builtin_amdgcn_mfma_f32_16x16x32_bf16(afrag, bfrag, acc[m], 0, 0, 0);
        }
    };
    // --------------------------------------------------------------------

    float4 xrA[4], xrB[4];
    float drA[8], drB[8];
    load_x(0, xrA);
    load_d(0, drA);

#pragma unroll 1
    for (int t = 0; t < NSTEP; t += 2) {
        __syncthreads();
        store_x(xrA);
        __syncthreads();
        load_x(t + 1, xrB);   // t+1 <= 63 always (t <= 62)
        load_d(t + 1, drB);
        compute(drA);

        __syncthreads();
        store_x(xrB);
        __syncthreads();
        if (t + 2 < NSTEP) {
            load_x(t + 2, xrA);
            load_d(t + 2, drA);
        }
        compute(drB);
    }

    // ---- epilogue ------------------------------------------------------
    // lane holds C[b = m*16 + g*4 + r][col]; sum relu over cols 0..9,
    // col 10 is the raw weight dot (scale by am), + bias
#pragma unroll
    for (int m = 0; m < 8; ++m) {
#pragma unroll
        for (int r = 0; r < 4; ++r) {
            float v = acc[m][r];
            float dend = (col < 10) ? fmaxf(v, 0.0f) : 0.0f;
#pragma unroll
            for (int s = 1; s < 16; s <<= 1)
                dend += __shfl_xor(dend, s, 64);
            float lin = __shfl(v, (lane & 48) | 10, 64);
            if (col == 0) {
                int b = m * 16 + g * 4 + r;
                out[(size_t)b * O_ + o] = dend + am * lin + bo;
            }
        }
    }
}

extern "C" void kernel_launch(void* const* d_in, const int* in_sizes, int n_in,
                              void* d_out, int out_size, void* d_ws, size_t ws_size,
                              hipStream_t stream) {
    const float* x     = (const float*)d_in[0];
    const float* ctx   = (const float*)d_in[1];
    // d_in[2] = prev_activation (unused by the reference output)
    const float* w     = (const float*)d_in[3];
    const float* bias  = (const float*)d_in[4];
    const float* astro = (const float*)d_in[5];
    const float* D     = (const float*)d_in[6];
    float* out = (float*)d_out;

    neuro_fused<<<dim3(O_ / 4), dim3(256), 0, stream>>>(x, ctx, w, bias, astro, D, out);
}